// Round 1
// baseline (1173.042 us; speedup 1.0000x reference)
//
#include <hip/hip_runtime.h>

#define N_NODES 16384
#define E_EDGES 524288
#define HID 128

// ---------------- CSR build ----------------

__global__ __launch_bounds__(256) void k_zero(int* __restrict__ cnt) {
    int i = blockIdx.x * 256 + threadIdx.x;
    if (i < N_NODES) cnt[i] = 0;
}

__global__ __launch_bounds__(256) void k_count(const int* __restrict__ ei, int* __restrict__ cnt) {
    int e = blockIdx.x * 256 + threadIdx.x;
    if (e < E_EDGES) {
        int d = ei[E_EDGES + e];
        atomicAdd(&cnt[d], 1);
    }
}

// single-block exclusive scan over 16384 counts; also dinv = rsqrt(deg+1), cursor init
__global__ __launch_bounds__(1024) void k_scan(const int* __restrict__ cnt, int* __restrict__ rp,
                                               int* __restrict__ cur, float* __restrict__ dinv) {
    __shared__ int part[1024];
    int t = threadIdx.x;
    int base = t * 16;
    int loc[16];
    int s = 0;
#pragma unroll
    for (int i = 0; i < 16; ++i) { loc[i] = cnt[base + i]; s += loc[i]; }
    part[t] = s;
    __syncthreads();
    for (int off = 1; off < 1024; off <<= 1) {
        int add = (t >= off) ? part[t - off] : 0;
        __syncthreads();
        part[t] += add;
        __syncthreads();
    }
    int excl = (t == 0) ? 0 : part[t - 1];
#pragma unroll
    for (int i = 0; i < 16; ++i) {
        rp[base + i] = excl;
        cur[base + i] = excl;
        dinv[base + i] = rsqrtf((float)(loc[i] + 1));  // +1 self-loop
        excl += loc[i];
    }
    if (t == 1023) rp[N_NODES] = excl;
}

__global__ __launch_bounds__(256) void k_fill(const int* __restrict__ ei, int* __restrict__ cur,
                                              int* __restrict__ eidx) {
    int e = blockIdx.x * 256 + threadIdx.x;
    if (e < E_EDGES) {
        int s = ei[e];
        int d = ei[E_EDGES + e];
        int p = atomicAdd(&cur[d], 1);
        eidx[p] = s;
    }
}

// ---------------- layer GEMMs ----------------

// t = X[N,16] @ W[16,128]; 2 rows per block
__global__ __launch_bounds__(256) void k_gemm16(const float* __restrict__ X, const float* __restrict__ W,
                                                float* __restrict__ T) {
    __shared__ float sW[16 * 128];
    int t = threadIdx.x;
#pragma unroll
    for (int i = 0; i < 8; ++i) sW[i * 256 + t] = W[i * 256 + t];
    __syncthreads();
    int row = blockIdx.x * 2 + (t >> 7);
    int c = t & 127;
    const float* xr = X + row * 16;
    float acc = 0.f;
#pragma unroll
    for (int k = 0; k < 16; ++k) acc = fmaf(xr[k], sW[k * 128 + c], acc);
    T[row * HID + c] = acc;
}

// T = A[N,128] @ W[128,128]; 64 rows per block, 4x8 micro-tile
__global__ __launch_bounds__(256) void k_gemm128(const float* __restrict__ A, const float* __restrict__ W,
                                                 float* __restrict__ T) {
    __shared__ float sA[64][132];
    __shared__ float sW[128][132];
    int t = threadIdx.x;
    int bm = blockIdx.x * 64;
#pragma unroll
    for (int it = 0; it < 8; ++it) {
        int f = it * 256 + t;
        int m = f >> 5, k4 = f & 31;
        *(float4*)(&sA[m][k4 * 4]) = *(const float4*)(A + (bm + m) * HID + k4 * 4);
    }
#pragma unroll
    for (int it = 0; it < 16; ++it) {
        int f = it * 256 + t;
        int k = f >> 5, n4 = f & 31;
        *(float4*)(&sW[k][n4 * 4]) = *(const float4*)(W + k * HID + n4 * 4);
    }
    __syncthreads();
    int tx = t & 15, ty = t >> 4;
    float acc[4][8] = {};
    for (int k4 = 0; k4 < 32; ++k4) {
        float4 a[4], b0[4], b1[4];
#pragma unroll
        for (int i = 0; i < 4; ++i) a[i] = *(const float4*)(&sA[ty * 4 + i][k4 * 4]);
#pragma unroll
        for (int kk = 0; kk < 4; ++kk) {
            b0[kk] = *(const float4*)(&sW[k4 * 4 + kk][tx * 4]);
            b1[kk] = *(const float4*)(&sW[k4 * 4 + kk][tx * 4 + 64]);
        }
#pragma unroll
        for (int kk = 0; kk < 4; ++kk) {
#pragma unroll
            for (int i = 0; i < 4; ++i) {
                float av = reinterpret_cast<const float*>(&a[i])[kk];
#pragma unroll
                for (int j = 0; j < 4; ++j) {
                    acc[i][j]     = fmaf(av, reinterpret_cast<const float*>(&b0[kk])[j], acc[i][j]);
                    acc[i][4 + j] = fmaf(av, reinterpret_cast<const float*>(&b1[kk])[j], acc[i][4 + j]);
                }
            }
        }
    }
#pragma unroll
    for (int i = 0; i < 4; ++i) {
        int row = bm + ty * 4 + i;
        float4 o0, o1;
        o0.x = acc[i][0]; o0.y = acc[i][1]; o0.z = acc[i][2]; o0.w = acc[i][3];
        o1.x = acc[i][4]; o1.y = acc[i][5]; o1.z = acc[i][6]; o1.w = acc[i][7];
        *(float4*)(T + row * HID + tx * 4) = o0;
        *(float4*)(T + row * HID + tx * 4 + 64) = o1;
    }
}

// ---------------- aggregation ----------------
// H[i][c] = relu(dinv[i]*(sum_{e: dst=i} dinv[src]*T[src][c] + dinv[i]*T[i][c]) + b[c])
__global__ __launch_bounds__(128) void k_agg(const float* __restrict__ T, const int* __restrict__ rp,
                                             const int* __restrict__ eidx, const float* __restrict__ dinv,
                                             const float* __restrict__ b, float* __restrict__ H) {
    __shared__ int se[128];
    __shared__ float sw[128];
    int i = blockIdx.x;
    int c = threadIdx.x;
    float di = dinv[i];
    float acc = di * T[i * HID + c];
    int beg = rp[i], end = rp[i + 1];
    for (int base = beg; base < end; base += 128) {
        int e = base + c;
        if (e < end) {
            int s = eidx[e];
            se[c] = s;
            sw[c] = dinv[s];
        }
        __syncthreads();
        int n = min(128, end - base);
        for (int j = 0; j < n; ++j) {
            acc += sw[j] * T[se[j] * HID + c];
        }
        __syncthreads();
    }
    float v = fmaf(di, acc, b[c]);
    H[i * HID + c] = fmaxf(v, 0.0f);
}

// ---------------- final FC: out[N,N] = H[N,128] @ Wfc[128,N] + bfc ----------------
__global__ __launch_bounds__(256) void k_fc(const float* __restrict__ A, const float* __restrict__ B,
                                            const float* __restrict__ bias, float* __restrict__ C) {
    __shared__ float sA[128][132];
    __shared__ float sB[128][132];
    int t = threadIdx.x;
    int bn = blockIdx.x * 128;
    int bm = blockIdx.y * 128;
#pragma unroll
    for (int it = 0; it < 16; ++it) {
        int f = it * 256 + t;
        int r = f >> 5, q4 = f & 31;
        *(float4*)(&sA[r][q4 * 4]) = *(const float4*)(A + (bm + r) * HID + q4 * 4);
        *(float4*)(&sB[r][q4 * 4]) = *(const float4*)(B + (size_t)r * N_NODES + bn + q4 * 4);
    }
    __syncthreads();
    int tx = t & 15, ty = t >> 4;
    float acc[8][8] = {};
    for (int k4 = 0; k4 < 32; ++k4) {
        float4 a[8];
#pragma unroll
        for (int r = 0; r < 2; ++r)
#pragma unroll
            for (int i = 0; i < 4; ++i)
                a[r * 4 + i] = *(const float4*)(&sA[r * 64 + ty * 4 + i][k4 * 4]);
#pragma unroll
        for (int kk = 0; kk < 4; ++kk) {
            float4 vb0 = *(const float4*)(&sB[k4 * 4 + kk][tx * 4]);
            float4 vb1 = *(const float4*)(&sB[k4 * 4 + kk][tx * 4 + 64]);
#pragma unroll
            for (int ri = 0; ri < 8; ++ri) {
                float av = reinterpret_cast<const float*>(&a[ri])[kk];
#pragma unroll
                for (int j = 0; j < 4; ++j) {
                    acc[ri][j]     = fmaf(av, reinterpret_cast<const float*>(&vb0)[j], acc[ri][j]);
                    acc[ri][4 + j] = fmaf(av, reinterpret_cast<const float*>(&vb1)[j], acc[ri][4 + j]);
                }
            }
        }
    }
    float bj0[4], bj1[4];
#pragma unroll
    for (int j = 0; j < 4; ++j) {
        bj0[j] = bias[bn + tx * 4 + j];
        bj1[j] = bias[bn + tx * 4 + 64 + j];
    }
#pragma unroll
    for (int ri = 0; ri < 8; ++ri) {
        int row = bm + (ri >> 2) * 64 + ty * 4 + (ri & 3);
        float* Crow = C + (size_t)row * N_NODES + bn;
        float4 o0, o1;
        o0.x = acc[ri][0] + bj0[0]; o0.y = acc[ri][1] + bj0[1];
        o0.z = acc[ri][2] + bj0[2]; o0.w = acc[ri][3] + bj0[3];
        o1.x = acc[ri][4] + bj1[0]; o1.y = acc[ri][5] + bj1[1];
        o1.z = acc[ri][6] + bj1[2]; o1.w = acc[ri][7] + bj1[3];
        *(float4*)(Crow + tx * 4) = o0;
        *(float4*)(Crow + tx * 4 + 64) = o1;
    }
}

// ---------------- launch ----------------

extern "C" void kernel_launch(void* const* d_in, const int* in_sizes, int n_in,
                              void* d_out, int out_size, void* d_ws, size_t ws_size,
                              hipStream_t stream) {
    const float* x   = (const float*)d_in[0];
    const int*   ei  = (const int*)d_in[1];
    const float* W1  = (const float*)d_in[2];
    const float* b1  = (const float*)d_in[3];
    const float* W2  = (const float*)d_in[4];
    const float* b2  = (const float*)d_in[5];
    const float* W3  = (const float*)d_in[6];
    const float* b3  = (const float*)d_in[7];
    const float* Wfc = (const float*)d_in[8];
    const float* bfc = (const float*)d_in[9];
    float* out = (float*)d_out;

    char* ws = (char*)d_ws;
    int* cnt  = (int*)ws;                   // 16384
    int* rp   = cnt + N_NODES;              // 16385 (+pad)
    int* cur  = rp + N_NODES + 64;          // 16384
    int* eidx = cur + N_NODES;              // E
    float* dinv = (float*)(eidx + E_EDGES); // 16384
    float* t  = dinv + N_NODES;             // N*128
    float* h  = t + N_NODES * HID;          // N*128

    k_zero<<<N_NODES / 256, 256, 0, stream>>>(cnt);
    k_count<<<E_EDGES / 256, 256, 0, stream>>>(ei, cnt);
    k_scan<<<1, 1024, 0, stream>>>(cnt, rp, cur, dinv);
    k_fill<<<E_EDGES / 256, 256, 0, stream>>>(ei, cur, eidx);

    // layer 1
    k_gemm16<<<N_NODES / 2, 256, 0, stream>>>(x, W1, t);
    k_agg<<<N_NODES, 128, 0, stream>>>(t, rp, eidx, dinv, b1, h);
    // layer 2
    k_gemm128<<<N_NODES / 64, 256, 0, stream>>>(h, W2, t);
    k_agg<<<N_NODES, 128, 0, stream>>>(t, rp, eidx, dinv, b2, h);
    // layer 3
    k_gemm128<<<N_NODES / 64, 256, 0, stream>>>(h, W3, t);
    k_agg<<<N_NODES, 128, 0, stream>>>(t, rp, eidx, dinv, b3, h);
    // final FC
    k_fc<<<dim3(N_NODES / 128, N_NODES / 128), 256, 0, stream>>>(h, Wfc, bfc, out);
}

// Round 2
// 638.803 us; speedup vs baseline: 1.8363x; 1.8363x over previous
//
#include <hip/hip_runtime.h>

#define N_NODES 16384
#define E_EDGES 524288
#define HID 128
#define LDSTR 132   // bf16 elements per LDS row (128 + 4 pad)

typedef __attribute__((ext_vector_type(8))) short bf16x8;
typedef __attribute__((ext_vector_type(4))) float f32x4;

__device__ __forceinline__ unsigned short f2bf(float x) {
    unsigned u = __builtin_bit_cast(unsigned, x);
    u = u + 0x7fff + ((u >> 16) & 1);
    return (unsigned short)(u >> 16);
}
__device__ __forceinline__ float bf2f(unsigned short h) {
    return __builtin_bit_cast(float, (unsigned)h << 16);
}

// ---------------- CSR build ----------------

__global__ __launch_bounds__(256) void k_zero(int* __restrict__ cnt) {
    int i = blockIdx.x * 256 + threadIdx.x;
    if (i < N_NODES) cnt[i] = 0;
}

__global__ __launch_bounds__(256) void k_count(const int* __restrict__ ei, int* __restrict__ cnt) {
    int e = blockIdx.x * 256 + threadIdx.x;
    if (e < E_EDGES) {
        int d = ei[E_EDGES + e];
        atomicAdd(&cnt[d], 1);
    }
}

__global__ __launch_bounds__(1024) void k_scan(const int* __restrict__ cnt, int* __restrict__ rp,
                                               int* __restrict__ cur, float* __restrict__ dinv) {
    __shared__ int part[1024];
    int t = threadIdx.x;
    int base = t * 16;
    int loc[16];
    int s = 0;
#pragma unroll
    for (int i = 0; i < 16; ++i) { loc[i] = cnt[base + i]; s += loc[i]; }
    part[t] = s;
    __syncthreads();
    for (int off = 1; off < 1024; off <<= 1) {
        int add = (t >= off) ? part[t - off] : 0;
        __syncthreads();
        part[t] += add;
        __syncthreads();
    }
    int excl = (t == 0) ? 0 : part[t - 1];
#pragma unroll
    for (int i = 0; i < 16; ++i) {
        rp[base + i] = excl;
        cur[base + i] = excl;
        dinv[base + i] = rsqrtf((float)(loc[i] + 1));  // +1 self-loop
        excl += loc[i];
    }
    if (t == 1023) rp[N_NODES] = excl;
}

__global__ __launch_bounds__(256) void k_fill(const int* __restrict__ ei, int* __restrict__ cur,
                                              int* __restrict__ eidx) {
    int e = blockIdx.x * 256 + threadIdx.x;
    if (e < E_EDGES) {
        int s = ei[e];
        int d = ei[E_EDGES + e];
        int p = atomicAdd(&cur[d], 1);
        eidx[p] = s;
    }
}

// ---------------- layer GEMMs (fp32, small share of runtime) ----------------

__global__ __launch_bounds__(256) void k_gemm16(const float* __restrict__ X, const float* __restrict__ W,
                                                float* __restrict__ T) {
    __shared__ float sW[16 * 128];
    int t = threadIdx.x;
#pragma unroll
    for (int i = 0; i < 8; ++i) sW[i * 256 + t] = W[i * 256 + t];
    __syncthreads();
    int row = blockIdx.x * 2 + (t >> 7);
    int c = t & 127;
    const float* xr = X + row * 16;
    float acc = 0.f;
#pragma unroll
    for (int k = 0; k < 16; ++k) acc = fmaf(xr[k], sW[k * 128 + c], acc);
    T[row * HID + c] = acc;
}

__global__ __launch_bounds__(256) void k_gemm128(const float* __restrict__ A, const float* __restrict__ W,
                                                 float* __restrict__ T) {
    __shared__ float sA[64][132];
    __shared__ float sW[128][132];
    int t = threadIdx.x;
    int bm = blockIdx.x * 64;
#pragma unroll
    for (int it = 0; it < 8; ++it) {
        int f = it * 256 + t;
        int m = f >> 5, k4 = f & 31;
        *(float4*)(&sA[m][k4 * 4]) = *(const float4*)(A + (bm + m) * HID + k4 * 4);
    }
#pragma unroll
    for (int it = 0; it < 16; ++it) {
        int f = it * 256 + t;
        int k = f >> 5, n4 = f & 31;
        *(float4*)(&sW[k][n4 * 4]) = *(const float4*)(W + k * HID + n4 * 4);
    }
    __syncthreads();
    int tx = t & 15, ty = t >> 4;
    float acc[4][8] = {};
    for (int k4 = 0; k4 < 32; ++k4) {
        float4 a[4], b0[4], b1[4];
#pragma unroll
        for (int i = 0; i < 4; ++i) a[i] = *(const float4*)(&sA[ty * 4 + i][k4 * 4]);
#pragma unroll
        for (int kk = 0; kk < 4; ++kk) {
            b0[kk] = *(const float4*)(&sW[k4 * 4 + kk][tx * 4]);
            b1[kk] = *(const float4*)(&sW[k4 * 4 + kk][tx * 4 + 64]);
        }
#pragma unroll
        for (int kk = 0; kk < 4; ++kk) {
#pragma unroll
            for (int i = 0; i < 4; ++i) {
                float av = reinterpret_cast<const float*>(&a[i])[kk];
#pragma unroll
                for (int j = 0; j < 4; ++j) {
                    acc[i][j]     = fmaf(av, reinterpret_cast<const float*>(&b0[kk])[j], acc[i][j]);
                    acc[i][4 + j] = fmaf(av, reinterpret_cast<const float*>(&b1[kk])[j], acc[i][4 + j]);
                }
            }
        }
    }
#pragma unroll
    for (int i = 0; i < 4; ++i) {
        int row = bm + ty * 4 + i;
        float4 o0, o1;
        o0.x = acc[i][0]; o0.y = acc[i][1]; o0.z = acc[i][2]; o0.w = acc[i][3];
        o1.x = acc[i][4]; o1.y = acc[i][5]; o1.z = acc[i][6]; o1.w = acc[i][7];
        *(float4*)(T + row * HID + tx * 4) = o0;
        *(float4*)(T + row * HID + tx * 4 + 64) = o1;
    }
}

// ---------------- aggregation ----------------
__global__ __launch_bounds__(128) void k_agg(const float* __restrict__ T, const int* __restrict__ rp,
                                             const int* __restrict__ eidx, const float* __restrict__ dinv,
                                             const float* __restrict__ b, float* __restrict__ H) {
    __shared__ int se[128];
    __shared__ float sw[128];
    int i = blockIdx.x;
    int c = threadIdx.x;
    float di = dinv[i];
    float acc = di * T[i * HID + c];
    int beg = rp[i], end = rp[i + 1];
    for (int base = beg; base < end; base += 128) {
        int e = base + c;
        if (e < end) {
            int s = eidx[e];
            se[c] = s;
            sw[c] = dinv[s];
        }
        __syncthreads();
        int n = min(128, end - base);
        for (int j = 0; j < n; ++j) {
            acc += sw[j] * T[se[j] * HID + c];
        }
        __syncthreads();
    }
    float v = fmaf(di, acc, b[c]);
    H[i * HID + c] = fmaxf(v, 0.0f);
}

// ---------------- bf16 split prep ----------------

// A[N,128] fp32 -> hi/lo bf16, same layout
__global__ __launch_bounds__(256) void k_split_a(const float* __restrict__ A,
                                                 unsigned short* __restrict__ hi,
                                                 unsigned short* __restrict__ lo) {
    int i = (blockIdx.x * 256 + threadIdx.x) * 8;
    float4 v0 = *(const float4*)(A + i);
    float4 v1 = *(const float4*)(A + i + 4);
    float v[8] = {v0.x, v0.y, v0.z, v0.w, v1.x, v1.y, v1.z, v1.w};
    alignas(16) unsigned short hb[8], lb[8];
#pragma unroll
    for (int j = 0; j < 8; ++j) {
        unsigned short h = f2bf(v[j]);
        hb[j] = h;
        lb[j] = f2bf(v[j] - bf2f(h));
    }
    *(uint4*)(hi + i) = *(uint4*)hb;
    *(uint4*)(lo + i) = *(uint4*)lb;
}

// W[128, N] fp32 -> transposed hi/lo bf16 [N,128] (K contiguous)
__global__ __launch_bounds__(256) void k_split_b(const float* __restrict__ W,
                                                 unsigned short* __restrict__ bhi,
                                                 unsigned short* __restrict__ blo) {
    __shared__ float sm[32][132];
    int t = threadIdx.x;
    int nb = blockIdx.x;   // 0..127
    int kb = blockIdx.y;   // 0..3
#pragma unroll
    for (int i = 0; i < 4; ++i) {
        int idx = i * 256 + t;         // 1024 float4 = 4096 floats
        int k = idx >> 5, n4 = idx & 31;
        *(float4*)(&sm[k][n4 * 4]) =
            *(const float4*)(W + (size_t)(kb * 32 + k) * N_NODES + nb * 128 + n4 * 4);
    }
    __syncthreads();
    int n = t >> 1, half = t & 1;
    alignas(16) unsigned short hb[16], lb[16];
#pragma unroll
    for (int j = 0; j < 16; ++j) {
        float x = sm[half * 16 + j][n];
        unsigned short h = f2bf(x);
        hb[j] = h;
        lb[j] = f2bf(x - bf2f(h));
    }
    size_t o = (size_t)(nb * 128 + n) * 128 + kb * 32 + half * 16;
    *(uint4*)(bhi + o) = *(uint4*)hb;
    *(uint4*)(bhi + o + 8) = *(uint4*)(hb + 8);
    *(uint4*)(blo + o) = *(uint4*)lb;
    *(uint4*)(blo + o + 8) = *(uint4*)(lb + 8);
}

// ---------------- final FC via MFMA, split-bf16 (3 MFMA / product) ----------------
// C[16384,16384] = A[16384,128] @ Wfc[128,16384] + bias
// A stored row-major bf16 hi/lo; B stored transposed [n][k] bf16 hi/lo.
__global__ __launch_bounds__(256, 1) void k_fc_mfma(const unsigned short* __restrict__ Ahi,
                                                    const unsigned short* __restrict__ Alo,
                                                    const unsigned short* __restrict__ Bhi,
                                                    const unsigned short* __restrict__ Blo,
                                                    const float* __restrict__ bias,
                                                    float* __restrict__ C) {
    __shared__ unsigned short sAhi[128 * LDSTR];
    __shared__ unsigned short sAlo[128 * LDSTR];
    __shared__ unsigned short sBhi[128 * LDSTR];
    __shared__ unsigned short sBlo[128 * LDSTR];
    int t = threadIdx.x;
    int bn = blockIdx.x, bm = blockIdx.y;

    // stage all 4 tiles (K=128 entirely resident; one barrier)
    {
        const unsigned short* g0 = Ahi + (size_t)bm * 128 * 128;
        const unsigned short* g1 = Alo + (size_t)bm * 128 * 128;
        const unsigned short* g2 = Bhi + (size_t)bn * 128 * 128;
        const unsigned short* g3 = Blo + (size_t)bn * 128 * 128;
#pragma unroll
        for (int it = 0; it < 8; ++it) {
            int c = it * 256 + t;            // 2048 chunks of 8 bf16
            int r = c >> 4, ko = (c & 15) * 8;
            *(uint4*)(sAhi + r * LDSTR + ko) = *(const uint4*)(g0 + r * 128 + ko);
            *(uint4*)(sAlo + r * LDSTR + ko) = *(const uint4*)(g1 + r * 128 + ko);
            *(uint4*)(sBhi + r * LDSTR + ko) = *(const uint4*)(g2 + r * 128 + ko);
            *(uint4*)(sBlo + r * LDSTR + ko) = *(const uint4*)(g3 + r * 128 + ko);
        }
    }
    __syncthreads();

    int wid = t >> 6, lane = t & 63;
    int wm = wid >> 1, wn = wid & 1;        // 2x2 waves, 64x64 each
    int row16 = lane & 15, kq = lane >> 4;  // fragment row/col + k-quarter

    f32x4 acc[4][4] = {};
#pragma unroll
    for (int ks = 0; ks < 4; ++ks) {
        bf16x8 ah[4], al[4], bh[4], bl[4];
        int ko = ks * 32 + kq * 8;
#pragma unroll
        for (int m = 0; m < 4; ++m) {
            int r = wm * 64 + m * 16 + row16;
            ah[m] = *(const bf16x8*)(sAhi + r * LDSTR + ko);
            al[m] = *(const bf16x8*)(sAlo + r * LDSTR + ko);
        }
#pragma unroll
        for (int n = 0; n < 4; ++n) {
            int r = wn * 64 + n * 16 + row16;
            bh[n] = *(const bf16x8*)(sBhi + r * LDSTR + ko);
            bl[n] = *(const bf16x8*)(sBlo + r * LDSTR + ko);
        }
#pragma unroll
        for (int m = 0; m < 4; ++m)
#pragma unroll
            for (int n = 0; n < 4; ++n) {
                acc[m][n] = __builtin_amdgcn_mfma_f32_16x16x32_bf16(ah[m], bh[n], acc[m][n], 0, 0, 0);
                acc[m][n] = __builtin_amdgcn_mfma_f32_16x16x32_bf16(ah[m], bl[n], acc[m][n], 0, 0, 0);
                acc[m][n] = __builtin_amdgcn_mfma_f32_16x16x32_bf16(al[m], bh[n], acc[m][n], 0, 0, 0);
            }
    }

    // epilogue: C/D layout col=lane&15, row=(lane>>4)*4+reg  [m89-verified]
#pragma unroll
    for (int n = 0; n < 4; ++n) {
        int col = bn * 128 + wn * 64 + n * 16 + row16;
        float bv = bias[col];
#pragma unroll
        for (int m = 0; m < 4; ++m) {
            int r0 = bm * 128 + wm * 64 + m * 16 + kq * 4;
#pragma unroll
            for (int r = 0; r < 4; ++r)
                C[(size_t)(r0 + r) * N_NODES + col] = acc[m][n][r] + bv;
        }
    }
}

// ---------------- launch ----------------

extern "C" void kernel_launch(void* const* d_in, const int* in_sizes, int n_in,
                              void* d_out, int out_size, void* d_ws, size_t ws_size,
                              hipStream_t stream) {
    const float* x   = (const float*)d_in[0];
    const int*   ei  = (const int*)d_in[1];
    const float* W1  = (const float*)d_in[2];
    const float* b1  = (const float*)d_in[3];
    const float* W2  = (const float*)d_in[4];
    const float* b2  = (const float*)d_in[5];
    const float* W3  = (const float*)d_in[6];
    const float* b3  = (const float*)d_in[7];
    const float* Wfc = (const float*)d_in[8];
    const float* bfc = (const float*)d_in[9];
    float* out = (float*)d_out;

    char* ws = (char*)d_ws;
    int* cnt  = (int*)ws;                   // 16384
    int* rp   = cnt + N_NODES;              // 16385 (+pad)
    int* cur  = rp + N_NODES + 64;          // 16384
    int* eidx = cur + N_NODES;              // E
    float* dinv = (float*)(eidx + E_EDGES); // 16384
    float* t  = dinv + N_NODES;             // N*128 fp32
    float* h  = t + N_NODES * HID;          // N*128 fp32
    // bf16 split buffers: A-splits reuse t's storage (t dead after last agg)
    unsigned short* ahi = (unsigned short*)t;            // N*128 bf16
    unsigned short* alo = ahi + N_NODES * HID;           // N*128 bf16 (== t's 8.4MB)
    unsigned short* bhi = (unsigned short*)(h + N_NODES * HID);  // N*128 bf16
    unsigned short* blo = bhi + N_NODES * HID;                   // N*128 bf16

    k_zero<<<N_NODES / 256, 256, 0, stream>>>(cnt);
    k_count<<<E_EDGES / 256, 256, 0, stream>>>(ei, cnt);
    k_scan<<<1, 1024, 0, stream>>>(cnt, rp, cur, dinv);
    k_fill<<<E_EDGES / 256, 256, 0, stream>>>(ei, cur, eidx);

    // layers
    k_gemm16<<<N_NODES / 2, 256, 0, stream>>>(x, W1, t);
    k_agg<<<N_NODES, 128, 0, stream>>>(t, rp, eidx, dinv, b1, h);
    k_gemm128<<<N_NODES / 64, 256, 0, stream>>>(h, W2, t);
    k_agg<<<N_NODES, 128, 0, stream>>>(t, rp, eidx, dinv, b2, h);
    k_gemm128<<<N_NODES / 64, 256, 0, stream>>>(h, W3, t);
    k_agg<<<N_NODES, 128, 0, stream>>>(t, rp, eidx, dinv, b3, h);

    // FC prep: split h and Wfc^T into bf16 hi/lo
    k_split_b<<<dim3(N_NODES / 128, HID / 32), 256, 0, stream>>>(Wfc, bhi, blo);
    k_split_a<<<(N_NODES * HID) / (256 * 8), 256, 0, stream>>>(h, ahi, alo);

    // final FC
    k_fc_mfma<<<dim3(N_NODES / 128, N_NODES / 128), 256, 0, stream>>>(ahi, alo, bhi, blo, bfc, out);
}